// Round 2
// baseline (996.477 us; speedup 1.0000x reference)
//
#include <hip/hip_runtime.h>

// Problem constants (fixed by reference):
#define F_DIM  4096
#define NROUNDS 12
#define GM     8192   // B*S
#define GN     4096   // F_OUT
#define GK     4096   // F_IN
#define BK2    128            // i8 K-tile (128 B row slice, same bytes as bf16 BK=64)
#define NIT2   (GK / BK2)     // 32

typedef int  int4v __attribute__((ext_vector_type(4)));
typedef signed char schar;

typedef __attribute__((address_space(3))) void lds_void;
typedef const __attribute__((address_space(1))) void glob_void;

__device__ __forceinline__ unsigned ordf(float f) {
    unsigned u = __float_as_uint(f);
    return (u & 0x80000000u) ? ~u : (u | 0x80000000u);
}
__device__ __forceinline__ float unordf(unsigned u) {
    unsigned v = (u & 0x80000000u) ? (u & 0x7fffffffu) : ~u;
    return __uint_as_float(v);
}

__global__ void init_mm_kernel(unsigned* mm) {
    if (threadIdx.x < 4) mm[threadIdx.x] = (threadIdx.x & 1) ? 0u : 0xFFFFFFFFu;
}

// ---------------------------------------------------------------------------
// Rotation: 4 rows/block, FEATURE-MAJOR LDS. buf[sig(f)] = float4 of rows 0..3
// at feature f, sig(f) = (f>>1) + (f&1)*2048. One ds_read_b128 gathers 4 rows.
// 512 threads/block (R2: was 256 -> only 8 waves/CU at 64KB LDS; 512 gives
// 16 waves/CU, same 2 blocks/CU, identical arithmetic order per feature).
// Metadata prefetched one round ahead (mats = 2048 float4/round, perms = 2048
// int2/round). Output: plain fp32 rows (exact), min/max -> mm via ord-atomics.
// ---------------------------------------------------------------------------
__global__ __launch_bounds__(512, 4)
void rotate_store_kernel(const float* __restrict__ src,
                         const int*   __restrict__ perms,
                         const float* __restrict__ mats,
                         unsigned*    __restrict__ mm,
                         float*       __restrict__ dst)
{
    __shared__ float4 buf[F_DIM];   // 64 KB
    const int t = threadIdx.x;
    const size_t r0 = (size_t)blockIdx.x * 4;
    const int2*   pbase = (const int2*)perms;    // 2048 int2 per round
    const float4* mbase = (const float4*)mats;   // 2048 float4 per round

    const float2* s0 = (const float2*)(src + (r0 + 0) * F_DIM);
    const float2* s1 = (const float2*)(src + (r0 + 1) * F_DIM);
    const float2* s2 = (const float2*)(src + (r0 + 2) * F_DIM);
    const float2* s3 = (const float2*)(src + (r0 + 3) * F_DIM);
    #pragma unroll
    for (int q = 0; q < 4; ++q) {
        const int e = t + q * 512;
        float2 a = s0[e], b = s1[e], c = s2[e], d = s3[e];
        buf[e]        = make_float4(a.x, b.x, c.x, d.x);
        buf[e + 2048] = make_float4(a.y, b.y, c.y, d.y);
    }
    __syncthreads();

    int2 pA[4], pB[4];
    float4 mA[4], mB[4];
    #pragma unroll
    for (int q = 0; q < 4; ++q) { int k = t + q * 512; pA[q] = pbase[k]; mA[q] = mbase[k]; }

    #pragma unroll 1
    for (int r = 0; r < NROUNDS; r += 2) {
        // ---- round r (meta in pA/mA), prefetch r+1 into pB/mB ----
        float4 va[4], vb[4];
        #pragma unroll
        for (int q = 0; q < 4; ++q) {
            int fa = pA[q].x, fb = pA[q].y;
            va[q] = buf[(fa >> 1) + ((fa & 1) << 11)];
            vb[q] = buf[(fb >> 1) + ((fb & 1) << 11)];
        }
        {
            const int2*   pr = pbase + (size_t)(r + 1) * 2048;
            const float4* mr = mbase + (size_t)(r + 1) * 2048;
            #pragma unroll
            for (int q = 0; q < 4; ++q) { int k = t + q * 512; pB[q] = pr[k]; mB[q] = mr[k]; }
        }
        __syncthreads();
        #pragma unroll
        for (int q = 0; q < 4; ++q) {
            const int k = t + q * 512;
            float4 A = va[q], B = vb[q], M = mA[q];
            buf[k]        = make_float4(M.x*A.x + M.y*B.x, M.x*A.y + M.y*B.y,
                                        M.x*A.z + M.y*B.z, M.x*A.w + M.y*B.w);
            buf[k + 2048] = make_float4(M.z*A.x + M.w*B.x, M.z*A.y + M.w*B.y,
                                        M.z*A.z + M.w*B.z, M.z*A.w + M.w*B.w);
        }
        __syncthreads();

        // ---- round r+1 (meta in pB/mB), prefetch r+2 into pA/mA ----
        #pragma unroll
        for (int q = 0; q < 4; ++q) {
            int fa = pB[q].x, fb = pB[q].y;
            va[q] = buf[(fa >> 1) + ((fa & 1) << 11)];
            vb[q] = buf[(fb >> 1) + ((fb & 1) << 11)];
        }
        if (r + 2 < NROUNDS) {
            const int2*   pr = pbase + (size_t)(r + 2) * 2048;
            const float4* mr = mbase + (size_t)(r + 2) * 2048;
            #pragma unroll
            for (int q = 0; q < 4; ++q) { int k = t + q * 512; pA[q] = pr[k]; mA[q] = mr[k]; }
        }
        __syncthreads();
        #pragma unroll
        for (int q = 0; q < 4; ++q) {
            const int k = t + q * 512;
            float4 A = va[q], B = vb[q], M = mB[q];
            buf[k]        = make_float4(M.x*A.x + M.y*B.x, M.x*A.y + M.y*B.y,
                                        M.x*A.z + M.y*B.z, M.x*A.w + M.y*B.w);
            buf[k + 2048] = make_float4(M.z*A.x + M.w*B.x, M.z*A.y + M.w*B.y,
                                        M.z*A.z + M.w*B.z, M.z*A.w + M.w*B.w);
        }
        __syncthreads();
    }

    // exact fp32 min/max + plain fp32 store (float2 per row per q)
    float lmin = __FLT_MAX__, lmax = -__FLT_MAX__;
    #pragma unroll
    for (int q = 0; q < 4; ++q) {
        const int e = t + q * 512;
        float4 f0 = buf[e];          // feature 2e,   rows 0..3
        float4 f1 = buf[e + 2048];   // feature 2e+1, rows 0..3
        lmin = fminf(lmin, fminf(fminf(f0.x, f0.y), fminf(f0.z, f0.w)));
        lmin = fminf(lmin, fminf(fminf(f1.x, f1.y), fminf(f1.z, f1.w)));
        lmax = fmaxf(lmax, fmaxf(fmaxf(f0.x, f0.y), fmaxf(f0.z, f0.w)));
        lmax = fmaxf(lmax, fmaxf(fmaxf(f1.x, f1.y), fmaxf(f1.z, f1.w)));
        ((float2*)(dst + (r0 + 0) * F_DIM))[e] = make_float2(f0.x, f1.x);
        ((float2*)(dst + (r0 + 1) * F_DIM))[e] = make_float2(f0.y, f1.y);
        ((float2*)(dst + (r0 + 2) * F_DIM))[e] = make_float2(f0.z, f1.z);
        ((float2*)(dst + (r0 + 3) * F_DIM))[e] = make_float2(f0.w, f1.w);
    }
    #pragma unroll
    for (int off = 32; off > 0; off >>= 1) {
        lmin = fminf(lmin, __shfl_down(lmin, off));
        lmax = fmaxf(lmax, __shfl_down(lmax, off));
    }
    if ((t & 63) == 0) {
        atomicMin(&mm[0], ordf(lmin));
        atomicMax(&mm[1], ordf(lmax));
    }
}

// ---------------------------------------------------------------------------
// Quantize one row per block from exact fp32: p = clip(rint((f-lo)/scale),0,255)
// (IEEE div + RNE = jnp.round path, validated previously). Store s8 = p-128 and
// the integer row-sum of s8 (needed by the i8 GEMM epilogue).
// ---------------------------------------------------------------------------
__global__ __launch_bounds__(256)
void quant_row_kernel(const float* __restrict__ src,
                      schar*       __restrict__ dst,
                      int*         __restrict__ rowsum,
                      const unsigned* __restrict__ mm, int sel)
{
    const int row = blockIdx.x, t = threadIdx.x;
    const float lo = unordf(mm[sel]);
    const float hi = unordf(mm[sel + 1]);
    const float scale = (hi - lo) / 255.0f;
    const float4* s = (const float4*)(src + (size_t)row * F_DIM);
    unsigned* d = (unsigned*)(dst + (size_t)row * F_DIM);
    int sum = 0;
    #pragma unroll
    for (int j = 0; j < 4; ++j) {
        const int c = t + 256 * j;
        float4 v = s[c];
        int p0 = (int)fminf(fmaxf(rintf((v.x - lo) / scale), 0.0f), 255.0f);
        int p1 = (int)fminf(fmaxf(rintf((v.y - lo) / scale), 0.0f), 255.0f);
        int p2 = (int)fminf(fmaxf(rintf((v.z - lo) / scale), 0.0f), 255.0f);
        int p3 = (int)fminf(fmaxf(rintf((v.w - lo) / scale), 0.0f), 255.0f);
        sum += p0 + p1 + p2 + p3 - 512;   // Σ (p-128)
        unsigned pack = ((unsigned)(p0 - 128) & 0xffu)
                      | (((unsigned)(p1 - 128) & 0xffu) << 8)
                      | (((unsigned)(p2 - 128) & 0xffu) << 16)
                      | (((unsigned)(p3 - 128) & 0xffu) << 24);
        d[c] = pack;
    }
    #pragma unroll
    for (int off = 32; off > 0; off >>= 1) sum += __shfl_down(sum, off);
    __shared__ int part[4];
    if ((t & 63) == 0) part[t >> 6] = sum;
    __syncthreads();
    if (t == 0) rowsum[row] = part[0] + part[1] + part[2] + part[3];
}

// ---------------------------------------------------------------------------
// i8 GEMM: C = dequant(A) * dequant(B)^T + bias, expanded exactly:
//   C[m,n] = ax*aw*Σ sx*sw + ax*cw*Rx[m] + aw*cx*Rw[n] + K*cx*cw + bias[n]
// 128x128 tile, BK2=128 (identical 128 B row-slice / 16 B-chunk XOR-swizzled
// LDS byte layout as the proven bf16 BK=64 kernel; NIT halves to 32).
// mfma_i32_16x16x64_i8: lane l holds A row=l&15, k=(l>>4)*16+j (16 B).
// ---------------------------------------------------------------------------
__global__ __launch_bounds__(256)
void gemm_i8_bias_kernel(const schar* __restrict__ A,
                         const schar* __restrict__ B,
                         const float* __restrict__ bias,
                         const int*   __restrict__ Rx,
                         const int*   __restrict__ Rw,
                         const unsigned* __restrict__ mm,
                         float*       __restrict__ C)
{
    __shared__ alignas(16) schar As[128 * 8 * 16];  // 16 KB: slot = row*8 + c
    __shared__ alignas(16) schar Bs[128 * 8 * 16];  // 16 KB
    const int t = threadIdx.x;
    // supertile: 8 consecutive mb x 32 nb per 256-block group
    const int bid = blockIdx.x;
    const int mb = (bid >> 8) * 8 + (bid & 7);
    const int nb = (bid >> 3) & 31;
    const int lane = t & 63, wv = t >> 6;
    const int wm = (wv & 1) * 64, wn = (wv >> 1) * 64;
    const int rr = lane & 15, kc = lane >> 4;

    const int srow = t >> 3;                     // row within 32-row group
    const int cg   = (t & 7) ^ (srow & 7);       // global 16B chunk (swizzled)
    const schar* pa = A + ((size_t)(mb * 128 + srow) * GK) + cg * 16;
    const schar* pb = B + ((size_t)(nb * 128 + srow) * GK) + cg * 16;

    int4v acc[4][4];
    const int4v zz = {0, 0, 0, 0};
    #pragma unroll
    for (int mi = 0; mi < 4; ++mi)
        #pragma unroll
        for (int ni = 0; ni < 4; ++ni)
            acc[mi][ni] = zz;

    auto stage = [&](int k0) {
        #pragma unroll
        for (int j = 0; j < 4; ++j) {
            __builtin_amdgcn_global_load_lds(
                (glob_void*)(pa + (size_t)j * 32 * GK + k0),
                (lds_void*)&As[(size_t)(wv * 64 + 256 * j) * 16], 16, 0, 0);
            __builtin_amdgcn_global_load_lds(
                (glob_void*)(pb + (size_t)j * 32 * GK + k0),
                (lds_void*)&Bs[(size_t)(wv * 64 + 256 * j) * 16], 16, 0, 0);
        }
    };

    stage(0);
    #pragma unroll 1
    for (int it = 0; it < NIT2; ++it) {
        __syncthreads();   // staging of tile `it` complete

        int4v af[2][4], bfr[2][4];
        #pragma unroll
        for (int kk = 0; kk < 2; ++kk) {
            #pragma unroll
            for (int mi = 0; mi < 4; ++mi)
                af[kk][mi] = *(const int4v*)
                    &As[(size_t)((wm + mi * 16 + rr) * 8 + ((kk * 4 + kc) ^ (rr & 7))) * 16];
            #pragma unroll
            for (int ni = 0; ni < 4; ++ni)
                bfr[kk][ni] = *(const int4v*)
                    &Bs[(size_t)((wn + ni * 16 + rr) * 8 + ((kk * 4 + kc) ^ (rr & 7))) * 16];
        }
        __syncthreads();   // all waves done reading -> LDS free for restage

        if (it + 1 < NIT2) stage((it + 1) * BK2);   // hides under MFMAs below

        #pragma unroll
        for (int kk = 0; kk < 2; ++kk)
            #pragma unroll
            for (int mi = 0; mi < 4; ++mi)
                #pragma unroll
                for (int ni = 0; ni < 4; ++ni)
                    acc[mi][ni] = __builtin_amdgcn_mfma_i32_16x16x64_i8(
                        af[kk][mi], bfr[kk][ni], acc[mi][ni], 0, 0, 0);
    }

    // epilogue: dequant expansion in fp32
    const float lox = unordf(mm[0]), hix = unordf(mm[1]);
    const float low = unordf(mm[2]), hiw = unordf(mm[3]);
    const float ax = (hix - lox) / 255.0f, aw = (hiw - low) / 255.0f;
    const float cx = 128.0f * ax + lox, cw = 128.0f * aw + low;
    const float sxw = ax * aw;
    const float kcc = (float)GK * cx * cw;
    const float axcw = ax * cw, awcx = aw * cx;

    float colt[4];
    #pragma unroll
    for (int ni = 0; ni < 4; ++ni) {
        const int col = nb * 128 + wn + ni * 16 + rr;
        colt[ni] = awcx * (float)Rw[col] + kcc + bias[col];
    }
    float rowt[4][4];
    #pragma unroll
    for (int mi = 0; mi < 4; ++mi)
        #pragma unroll
        for (int r = 0; r < 4; ++r)
            rowt[mi][r] = axcw * (float)Rx[mb * 128 + wm + mi * 16 + kc * 4 + r];

    // C/D layout: row-in-16 = kc*4 + reg, col-in-16 = rr (dtype-independent)
    #pragma unroll
    for (int mi = 0; mi < 4; ++mi) {
        #pragma unroll
        for (int ni = 0; ni < 4; ++ni) {
            const int col = nb * 128 + wn + ni * 16 + rr;
            #pragma unroll
            for (int r = 0; r < 4; ++r) {
                const int row = mb * 128 + wm + mi * 16 + kc * 4 + r;
                C[(size_t)row * GN + col] =
                    sxw * (float)acc[mi][ni][r] + rowt[mi][r] + colt[ni];
            }
        }
    }
}

extern "C" void kernel_launch(void* const* d_in, const int* in_sizes, int n_in,
                              void* d_out, int out_size, void* d_ws, size_t ws_size,
                              hipStream_t stream)
{
    (void)in_sizes; (void)n_in; (void)out_size; (void)ws_size;
    const float* x     = (const float*)d_in[0];
    const float* w     = (const float*)d_in[1];
    const float* bias  = (const float*)d_in[2];
    const float* mats  = (const float*)d_in[3];
    const int*   perms = (const int*)d_in[4];
    float* out = (float*)d_out;

    // ws layout (<= 96 MiB + small, same budget as proven before):
    //   [0,64M):   w_rot fp32 (64 MiB), dead after quant_w; then reused:
    //              [0,32M) xq8 int8, [32M,+32K) Rx
    //   [64M,80M): wq8 int8 (16 MiB)
    //   [80M,+16K): Rw
    //   [81M,+16B): mm
    // d_out: x_rot fp32 (exactly 128 MiB), dead after quant_x; GEMM writes C.
    char* ws = (char*)d_ws;
    float*    wrot = (float*)ws;
    schar*    xq8  = (schar*)ws;
    int*      Rx   = (int*)(ws + (size_t)32 * 1024 * 1024);
    schar*    wq8  = (schar*)(ws + (size_t)64 * 1024 * 1024);
    int*      Rw   = (int*)(ws + (size_t)80 * 1024 * 1024);
    unsigned* mm   = (unsigned*)(ws + (size_t)81 * 1024 * 1024);
    float*    xrot = out;

    init_mm_kernel<<<1, 64, 0, stream>>>(mm);
    // W chain first so its fp32 scratch region can be reused for xq8
    rotate_store_kernel<<<GN / 4, 512, 0, stream>>>(w, perms, mats, mm + 2, wrot);
    quant_row_kernel<<<GN, 256, 0, stream>>>(wrot, wq8, Rw, mm, 2);
    // X chain: fp32 into d_out (exact fit), int8 into dead w_rot region
    rotate_store_kernel<<<GM / 4, 512, 0, stream>>>(x, perms, mats, mm + 0, xrot);
    quant_row_kernel<<<GM, 256, 0, stream>>>(xrot, xq8, Rx, mm, 0);
    gemm_i8_bias_kernel<<<GM / 128 * GN / 128, 256, 0, stream>>>(
        xq8, wq8, bias, Rx, Rw, mm, out);
}

// Round 3
// 703.731 us; speedup vs baseline: 1.4160x; 1.4160x over previous
//
#include <hip/hip_runtime.h>

// Problem constants (fixed by reference):
#define F_DIM  4096
#define NROUNDS 12
#define GM     8192   // B*S
#define GN     4096   // F_OUT
#define GK     4096   // F_IN
#define BK2    128            // i8 K-tile (128 B row slice, same bytes as bf16 BK=64)
#define NIT2   (GK / BK2)     // 32

typedef int  int4v __attribute__((ext_vector_type(4)));
typedef signed char schar;

typedef __attribute__((address_space(3))) void lds_void;
typedef const __attribute__((address_space(1))) void glob_void;

__device__ __forceinline__ unsigned ordf(float f) {
    unsigned u = __float_as_uint(f);
    return (u & 0x80000000u) ? ~u : (u | 0x80000000u);
}
__device__ __forceinline__ float unordf(unsigned u) {
    unsigned v = (u & 0x80000000u) ? (u & 0x7fffffffu) : ~u;
    return __uint_as_float(v);
}

__global__ void init_mm_kernel(unsigned* mm) {
    if (threadIdx.x < 4) mm[threadIdx.x] = (threadIdx.x & 1) ? 0u : 0xFFFFFFFFu;
}

// ---------------------------------------------------------------------------
// Rotation: 4 rows/block, FEATURE-MAJOR LDS. buf[sig(f)] = float4 of rows 0..3
// at feature f, sig(f) = (f>>1) + (f&1)*2048. One ds_read_b128 gathers 4 rows.
// 256 threads/block (R2 lesson: 512t halves per-wave gather ILP -> 1.7x
// slower; the binding resource is in-flight LDS ops per wave, not wave count).
// R3: last round fused into the store (compute in regs -> direct global
// store; removes 16 w + 16 r b128 + 1 barrier per block, bit-identical), and
// W+X rotates combined into one launch (W = blocks [0,1024), X = rest) so the
// W tail overlaps the X head.
// Metadata prefetched one round ahead (mats = 2048 float4/round, perms = 2048
// int2/round). Output: plain fp32 rows (exact), min/max -> mm via ord-atomics.
// ---------------------------------------------------------------------------
__global__ __launch_bounds__(256)
void rotate_store_kernel(const float* __restrict__ xsrc,
                         const float* __restrict__ wsrc,
                         const int*   __restrict__ perms,
                         const float* __restrict__ mats,
                         unsigned*    __restrict__ mm,
                         float*       __restrict__ xdst,
                         float*       __restrict__ wdst)
{
    __shared__ float4 buf[F_DIM];   // 64 KB
    const int t = threadIdx.x;
    const int b = blockIdx.x;
    const bool isW = b < (GN / 4);
    const float* __restrict__ src = isW ? wsrc : xsrc;
    float* __restrict__ dst = isW ? wdst : xdst;
    unsigned* mmp = mm + (isW ? 2 : 0);
    const size_t r0 = (size_t)(isW ? b : b - GN / 4) * 4;

    const int2*   pbase = (const int2*)perms;    // 2048 int2 per round
    const float4* mbase = (const float4*)mats;   // 2048 float4 per round

    const float2* s0 = (const float2*)(src + (r0 + 0) * F_DIM);
    const float2* s1 = (const float2*)(src + (r0 + 1) * F_DIM);
    const float2* s2 = (const float2*)(src + (r0 + 2) * F_DIM);
    const float2* s3 = (const float2*)(src + (r0 + 3) * F_DIM);
    #pragma unroll
    for (int q = 0; q < 8; ++q) {
        const int e = t + q * 256;
        float2 a = s0[e], b2 = s1[e], c = s2[e], d = s3[e];
        buf[e]        = make_float4(a.x, b2.x, c.x, d.x);
        buf[e + 2048] = make_float4(a.y, b2.y, c.y, d.y);
    }
    __syncthreads();

    int2 pA[8], pB[8];
    float4 mA[8], mB[8];
    #pragma unroll
    for (int q = 0; q < 8; ++q) { int k = t + q * 256; pA[q] = pbase[k]; mA[q] = mbase[k]; }

    // rounds 0..9 (pair loop); leaves round-10 meta in pA/mA
    #pragma unroll 1
    for (int r = 0; r < 10; r += 2) {
        // ---- round r (meta in pA/mA), prefetch r+1 into pB/mB ----
        float4 va[8], vb[8];
        #pragma unroll
        for (int q = 0; q < 8; ++q) {
            int fa = pA[q].x, fb = pA[q].y;
            va[q] = buf[(fa >> 1) + ((fa & 1) << 11)];
            vb[q] = buf[(fb >> 1) + ((fb & 1) << 11)];
        }
        {
            const int2*   pr = pbase + (size_t)(r + 1) * 2048;
            const float4* mr = mbase + (size_t)(r + 1) * 2048;
            #pragma unroll
            for (int q = 0; q < 8; ++q) { int k = t + q * 256; pB[q] = pr[k]; mB[q] = mr[k]; }
        }
        __syncthreads();
        #pragma unroll
        for (int q = 0; q < 8; ++q) {
            const int k = t + q * 256;
            float4 A = va[q], B = vb[q], M = mA[q];
            buf[k]        = make_float4(M.x*A.x + M.y*B.x, M.x*A.y + M.y*B.y,
                                        M.x*A.z + M.y*B.z, M.x*A.w + M.y*B.w);
            buf[k + 2048] = make_float4(M.z*A.x + M.w*B.x, M.z*A.y + M.w*B.y,
                                        M.z*A.z + M.w*B.z, M.z*A.w + M.w*B.w);
        }
        __syncthreads();

        // ---- round r+1 (meta in pB/mB), prefetch r+2 into pA/mA ----
        #pragma unroll
        for (int q = 0; q < 8; ++q) {
            int fa = pB[q].x, fb = pB[q].y;
            va[q] = buf[(fa >> 1) + ((fa & 1) << 11)];
            vb[q] = buf[(fb >> 1) + ((fb & 1) << 11)];
        }
        {
            const int2*   pr = pbase + (size_t)(r + 2) * 2048;
            const float4* mr = mbase + (size_t)(r + 2) * 2048;
            #pragma unroll
            for (int q = 0; q < 8; ++q) { int k = t + q * 256; pA[q] = pr[k]; mA[q] = mr[k]; }
        }
        __syncthreads();
        #pragma unroll
        for (int q = 0; q < 8; ++q) {
            const int k = t + q * 256;
            float4 A = va[q], B = vb[q], M = mB[q];
            buf[k]        = make_float4(M.x*A.x + M.y*B.x, M.x*A.y + M.y*B.y,
                                        M.x*A.z + M.y*B.z, M.x*A.w + M.y*B.w);
            buf[k + 2048] = make_float4(M.z*A.x + M.w*B.x, M.z*A.y + M.w*B.y,
                                        M.z*A.z + M.w*B.z, M.z*A.w + M.w*B.w);
        }
        __syncthreads();
    }

    // ---- round 10 (meta in pA/mA), prefetch round 11 into pB/mB ----
    {
        float4 va[8], vb[8];
        #pragma unroll
        for (int q = 0; q < 8; ++q) {
            int fa = pA[q].x, fb = pA[q].y;
            va[q] = buf[(fa >> 1) + ((fa & 1) << 11)];
            vb[q] = buf[(fb >> 1) + ((fb & 1) << 11)];
        }
        {
            const int2*   pr = pbase + (size_t)11 * 2048;
            const float4* mr = mbase + (size_t)11 * 2048;
            #pragma unroll
            for (int q = 0; q < 8; ++q) { int k = t + q * 256; pB[q] = pr[k]; mB[q] = mr[k]; }
        }
        __syncthreads();
        #pragma unroll
        for (int q = 0; q < 8; ++q) {
            const int k = t + q * 256;
            float4 A = va[q], B = vb[q], M = mA[q];
            buf[k]        = make_float4(M.x*A.x + M.y*B.x, M.x*A.y + M.y*B.y,
                                        M.x*A.z + M.y*B.z, M.x*A.w + M.y*B.w);
            buf[k + 2048] = make_float4(M.z*A.x + M.w*B.x, M.z*A.y + M.w*B.y,
                                        M.z*A.z + M.w*B.z, M.z*A.w + M.w*B.w);
        }
        __syncthreads();
    }

    // ---- round 11 fused with store: compute in registers, store directly.
    // f0/f1 are exactly the values the old code wrote to buf[k]/buf[k+2048]
    // and re-read in the store phase -> bit-identical output and min/max.
    float lmin = __FLT_MAX__, lmax = -__FLT_MAX__;
    {
        float4 va[8], vb[8];
        #pragma unroll
        for (int q = 0; q < 8; ++q) {
            int fa = pB[q].x, fb = pB[q].y;
            va[q] = buf[(fa >> 1) + ((fa & 1) << 11)];
            vb[q] = buf[(fb >> 1) + ((fb & 1) << 11)];
        }
        #pragma unroll
        for (int q = 0; q < 8; ++q) {
            const int e = t + q * 256;
            float4 A = va[q], B = vb[q], M = mB[q];
            float4 f0 = make_float4(M.x*A.x + M.y*B.x, M.x*A.y + M.y*B.y,
                                    M.x*A.z + M.y*B.z, M.x*A.w + M.y*B.w);
            float4 f1 = make_float4(M.z*A.x + M.w*B.x, M.z*A.y + M.w*B.y,
                                    M.z*A.z + M.w*B.z, M.z*A.w + M.w*B.w);
            lmin = fminf(lmin, fminf(fminf(f0.x, f0.y), fminf(f0.z, f0.w)));
            lmin = fminf(lmin, fminf(fminf(f1.x, f1.y), fminf(f1.z, f1.w)));
            lmax = fmaxf(lmax, fmaxf(fmaxf(f0.x, f0.y), fmaxf(f0.z, f0.w)));
            lmax = fmaxf(lmax, fmaxf(fmaxf(f1.x, f1.y), fmaxf(f1.z, f1.w)));
            ((float2*)(dst + (r0 + 0) * F_DIM))[e] = make_float2(f0.x, f1.x);
            ((float2*)(dst + (r0 + 1) * F_DIM))[e] = make_float2(f0.y, f1.y);
            ((float2*)(dst + (r0 + 2) * F_DIM))[e] = make_float2(f0.z, f1.z);
            ((float2*)(dst + (r0 + 3) * F_DIM))[e] = make_float2(f0.w, f1.w);
        }
    }
    #pragma unroll
    for (int off = 32; off > 0; off >>= 1) {
        lmin = fminf(lmin, __shfl_down(lmin, off));
        lmax = fmaxf(lmax, __shfl_down(lmax, off));
    }
    if ((t & 63) == 0) {
        atomicMin(&mmp[0], ordf(lmin));
        atomicMax(&mmp[1], ordf(lmax));
    }
}

// ---------------------------------------------------------------------------
// Quantize one row per block from exact fp32: p = clip(rint((f-lo)/scale),0,255)
// (IEEE div + RNE = jnp.round path, validated previously). Store s8 = p-128 and
// the integer row-sum of s8 (needed by the i8 GEMM epilogue).
// ---------------------------------------------------------------------------
__global__ __launch_bounds__(256)
void quant_row_kernel(const float* __restrict__ src,
                      schar*       __restrict__ dst,
                      int*         __restrict__ rowsum,
                      const unsigned* __restrict__ mm, int sel)
{
    const int row = blockIdx.x, t = threadIdx.x;
    const float lo = unordf(mm[sel]);
    const float hi = unordf(mm[sel + 1]);
    const float scale = (hi - lo) / 255.0f;
    const float4* s = (const float4*)(src + (size_t)row * F_DIM);
    unsigned* d = (unsigned*)(dst + (size_t)row * F_DIM);
    int sum = 0;
    #pragma unroll
    for (int j = 0; j < 4; ++j) {
        const int c = t + 256 * j;
        float4 v = s[c];
        int p0 = (int)fminf(fmaxf(rintf((v.x - lo) / scale), 0.0f), 255.0f);
        int p1 = (int)fminf(fmaxf(rintf((v.y - lo) / scale), 0.0f), 255.0f);
        int p2 = (int)fminf(fmaxf(rintf((v.z - lo) / scale), 0.0f), 255.0f);
        int p3 = (int)fminf(fmaxf(rintf((v.w - lo) / scale), 0.0f), 255.0f);
        sum += p0 + p1 + p2 + p3 - 512;   // Σ (p-128)
        unsigned pack = ((unsigned)(p0 - 128) & 0xffu)
                      | (((unsigned)(p1 - 128) & 0xffu) << 8)
                      | (((unsigned)(p2 - 128) & 0xffu) << 16)
                      | (((unsigned)(p3 - 128) & 0xffu) << 24);
        d[c] = pack;
    }
    #pragma unroll
    for (int off = 32; off > 0; off >>= 1) sum += __shfl_down(sum, off);
    __shared__ int part[4];
    if ((t & 63) == 0) part[t >> 6] = sum;
    __syncthreads();
    if (t == 0) rowsum[row] = part[0] + part[1] + part[2] + part[3];
}

// ---------------------------------------------------------------------------
// i8 GEMM: C = dequant(A) * dequant(B)^T + bias, expanded exactly:
//   C[m,n] = ax*aw*Σ sx*sw + ax*cw*Rx[m] + aw*cx*Rw[n] + K*cx*cw + bias[n]
// 128x128 tile, BK2=128 (identical 128 B row-slice / 16 B-chunk XOR-swizzled
// LDS byte layout as the proven bf16 BK=64 kernel; NIT halves to 32).
// mfma_i32_16x16x64_i8: lane l holds A row=l&15, k=(l>>4)*16+j (16 B).
// ---------------------------------------------------------------------------
__global__ __launch_bounds__(256)
void gemm_i8_bias_kernel(const schar* __restrict__ A,
                         const schar* __restrict__ B,
                         const float* __restrict__ bias,
                         const int*   __restrict__ Rx,
                         const int*   __restrict__ Rw,
                         const unsigned* __restrict__ mm,
                         float*       __restrict__ C)
{
    __shared__ alignas(16) schar As[128 * 8 * 16];  // 16 KB: slot = row*8 + c
    __shared__ alignas(16) schar Bs[128 * 8 * 16];  // 16 KB
    const int t = threadIdx.x;
    // supertile: 8 consecutive mb x 32 nb per 256-block group
    const int bid = blockIdx.x;
    const int mb = (bid >> 8) * 8 + (bid & 7);
    const int nb = (bid >> 3) & 31;
    const int lane = t & 63, wv = t >> 6;
    const int wm = (wv & 1) * 64, wn = (wv >> 1) * 64;
    const int rr = lane & 15, kc = lane >> 4;

    const int srow = t >> 3;                     // row within 32-row group
    const int cg   = (t & 7) ^ (srow & 7);       // global 16B chunk (swizzled)
    const schar* pa = A + ((size_t)(mb * 128 + srow) * GK) + cg * 16;
    const schar* pb = B + ((size_t)(nb * 128 + srow) * GK) + cg * 16;

    int4v acc[4][4];
    const int4v zz = {0, 0, 0, 0};
    #pragma unroll
    for (int mi = 0; mi < 4; ++mi)
        #pragma unroll
        for (int ni = 0; ni < 4; ++ni)
            acc[mi][ni] = zz;

    auto stage = [&](int k0) {
        #pragma unroll
        for (int j = 0; j < 4; ++j) {
            __builtin_amdgcn_global_load_lds(
                (glob_void*)(pa + (size_t)j * 32 * GK + k0),
                (lds_void*)&As[(size_t)(wv * 64 + 256 * j) * 16], 16, 0, 0);
            __builtin_amdgcn_global_load_lds(
                (glob_void*)(pb + (size_t)j * 32 * GK + k0),
                (lds_void*)&Bs[(size_t)(wv * 64 + 256 * j) * 16], 16, 0, 0);
        }
    };

    stage(0);
    #pragma unroll 1
    for (int it = 0; it < NIT2; ++it) {
        __syncthreads();   // staging of tile `it` complete

        int4v af[2][4], bfr[2][4];
        #pragma unroll
        for (int kk = 0; kk < 2; ++kk) {
            #pragma unroll
            for (int mi = 0; mi < 4; ++mi)
                af[kk][mi] = *(const int4v*)
                    &As[(size_t)((wm + mi * 16 + rr) * 8 + ((kk * 4 + kc) ^ (rr & 7))) * 16];
            #pragma unroll
            for (int ni = 0; ni < 4; ++ni)
                bfr[kk][ni] = *(const int4v*)
                    &Bs[(size_t)((wn + ni * 16 + rr) * 8 + ((kk * 4 + kc) ^ (rr & 7))) * 16];
        }
        __syncthreads();   // all waves done reading -> LDS free for restage

        if (it + 1 < NIT2) stage((it + 1) * BK2);   // hides under MFMAs below

        #pragma unroll
        for (int kk = 0; kk < 2; ++kk)
            #pragma unroll
            for (int mi = 0; mi < 4; ++mi)
                #pragma unroll
                for (int ni = 0; ni < 4; ++ni)
                    acc[mi][ni] = __builtin_amdgcn_mfma_i32_16x16x64_i8(
                        af[kk][mi], bfr[kk][ni], acc[mi][ni], 0, 0, 0);
    }

    // epilogue: dequant expansion in fp32
    const float lox = unordf(mm[0]), hix = unordf(mm[1]);
    const float low = unordf(mm[2]), hiw = unordf(mm[3]);
    const float ax = (hix - lox) / 255.0f, aw = (hiw - low) / 255.0f;
    const float cx = 128.0f * ax + lox, cw = 128.0f * aw + low;
    const float sxw = ax * aw;
    const float kcc = (float)GK * cx * cw;
    const float axcw = ax * cw, awcx = aw * cx;

    float colt[4];
    #pragma unroll
    for (int ni = 0; ni < 4; ++ni) {
        const int col = nb * 128 + wn + ni * 16 + rr;
        colt[ni] = awcx * (float)Rw[col] + kcc + bias[col];
    }
    float rowt[4][4];
    #pragma unroll
    for (int mi = 0; mi < 4; ++mi)
        #pragma unroll
        for (int r = 0; r < 4; ++r)
            rowt[mi][r] = axcw * (float)Rx[mb * 128 + wm + mi * 16 + kc * 4 + r];

    // C/D layout: row-in-16 = kc*4 + reg, col-in-16 = rr (dtype-independent)
    #pragma unroll
    for (int mi = 0; mi < 4; ++mi) {
        #pragma unroll
        for (int ni = 0; ni < 4; ++ni) {
            const int col = nb * 128 + wn + ni * 16 + rr;
            #pragma unroll
            for (int r = 0; r < 4; ++r) {
                const int row = mb * 128 + wm + mi * 16 + kc * 4 + r;
                C[(size_t)row * GN + col] =
                    sxw * (float)acc[mi][ni][r] + rowt[mi][r] + colt[ni];
            }
        }
    }
}

extern "C" void kernel_launch(void* const* d_in, const int* in_sizes, int n_in,
                              void* d_out, int out_size, void* d_ws, size_t ws_size,
                              hipStream_t stream)
{
    (void)in_sizes; (void)n_in; (void)out_size; (void)ws_size;
    const float* x     = (const float*)d_in[0];
    const float* w     = (const float*)d_in[1];
    const float* bias  = (const float*)d_in[2];
    const float* mats  = (const float*)d_in[3];
    const int*   perms = (const int*)d_in[4];
    float* out = (float*)d_out;

    // ws layout (<= 96 MiB + small, same budget as proven before):
    //   [0,64M):   w_rot fp32 (64 MiB), dead after quant_w; then reused:
    //              [0,32M) xq8 int8, [32M,+32K) Rx
    //   [64M,80M): wq8 int8 (16 MiB)
    //   [80M,+16K): Rw
    //   [81M,+16B): mm
    // d_out: x_rot fp32 (exactly 128 MiB), dead after quant_x; GEMM writes C.
    char* ws = (char*)d_ws;
    float*    wrot = (float*)ws;
    schar*    xq8  = (schar*)ws;
    int*      Rx   = (int*)(ws + (size_t)32 * 1024 * 1024);
    schar*    wq8  = (schar*)(ws + (size_t)64 * 1024 * 1024);
    int*      Rw   = (int*)(ws + (size_t)80 * 1024 * 1024);
    unsigned* mm   = (unsigned*)(ws + (size_t)81 * 1024 * 1024);
    float*    xrot = out;

    init_mm_kernel<<<1, 64, 0, stream>>>(mm);
    // combined W+X rotate: blocks [0, GN/4) = W, [GN/4, GN/4+GM/4) = X
    rotate_store_kernel<<<GN / 4 + GM / 4, 256, 0, stream>>>(
        x, w, perms, mats, mm, xrot, wrot);
    // quant_w first: it reads wrot before quant_x overwrites that region (xq8)
    quant_row_kernel<<<GN, 256, 0, stream>>>(wrot, wq8, Rw, mm, 2);
    quant_row_kernel<<<GM, 256, 0, stream>>>(xrot, xq8, Rx, mm, 0);
    gemm_i8_bias_kernel<<<GM / 128 * GN / 128, 256, 0, stream>>>(
        xq8, wq8, bias, Rx, Rw, mm, out);
}